// Round 5
// baseline (125.102 us; speedup 1.0000x reference)
//
#include <hip/hip_runtime.h>
#include <hip/hip_bf16.h>

// Problem: out[b] = (inv(A[a[b]]) @ B_rep[a[b]] @ A[a[b]]) @ x[b]
// BATCH=500000, DIM=16, N_ACTIONS=8
// Inputs: x[500000*16] f32, a[500000] i32, A[8*16*16] f32, B_rep[8*16*16] f32
// Output: [500000*16] f32

#define N_ACTIONS 8
#define DIM 16
// LDS action stride: 260 % 32 == 4 dwords, so the 8 actions' uniform-offset
// 16B reads land in 8 disjoint 4-bank groups -> conflict-free broadcast.
// 260*4 = 1040 B keeps 16-B alignment for b128 reads.
#define W_STRIDE 260
#define NBLK2 1024  // grid for kernel 2: 4 blocks/CU, ~488 samples/block

typedef float v4f __attribute__((ext_vector_type(4)));

// ---------------------------------------------------------------------------
// Kernel 1: W[n] = inv(A[n]) @ B_rep[n] @ A[n], one block per action.
// Gauss-Jordan WITHOUT pivoting (A = I + 0.1*N(0,1), near-unit diagonal,
// well-conditioned): read-phase / write-phase = 2 barriers per iteration.
// ---------------------------------------------------------------------------
__global__ __launch_bounds__(256) void compute_W_kernel(
    const float* __restrict__ A, const float* __restrict__ Brep,
    float* __restrict__ Wg) {
  __shared__ float M[DIM][DIM + 1];
  __shared__ float Inv[DIM][DIM + 1];
  __shared__ float As[DIM][DIM + 1];
  __shared__ float Bs[DIM][DIM + 1];
  __shared__ float Cs[DIM][DIM + 1];

  const int n = blockIdx.x;
  const int tid = threadIdx.x;
  const int i = tid >> 4;
  const int j = tid & 15;

  const float a_ij = A[n * 256 + i * 16 + j];
  M[i][j] = a_ij;
  As[i][j] = a_ij;
  Bs[i][j] = Brep[n * 256 + i * 16 + j];
  Inv[i][j] = (i == j) ? 1.0f : 0.0f;
  __syncthreads();

#pragma unroll 1
  for (int k = 0; k < DIM; ++k) {
    // read phase: everything this thread needs, before anyone writes
    const float mkk = M[k][k];
    const float f = M[i][k];
    const float mkj = M[k][j];
    const float ikj = Inv[k][j];
    __syncthreads();
    const float pivinv = 1.0f / mkk;
    if (i == k) {
      M[k][j] = mkj * pivinv;
      Inv[k][j] = ikj * pivinv;
    } else {
      const float t = f * pivinv;
      M[i][j] -= t * mkj;
      Inv[i][j] -= t * ikj;
    }
    __syncthreads();
  }

  // C = B_rep @ A
  float acc = 0.0f;
#pragma unroll
  for (int k = 0; k < DIM; ++k) acc += Bs[i][k] * As[k][j];
  Cs[i][j] = acc;
  __syncthreads();

  // W = inv(A) @ C
  float w = 0.0f;
#pragma unroll
  for (int k = 0; k < DIM; ++k) w += Inv[i][k] * Cs[k][j];
  Wg[n * 256 + i * 16 + j] = w;
}

// ---------------------------------------------------------------------------
// Kernel 2: out[b] = W[a[b]] @ x[b]. Grid-stride, one thread per sample per
// iteration. W staged once per block in padded LDS (conflict-free broadcast).
// x loads / out stores vectorized 16B and nontemporal (pure stream).
// ---------------------------------------------------------------------------
__global__ __launch_bounds__(256) void gather_matvec_kernel(
    const float* __restrict__ x, const int* __restrict__ a,
    const float* __restrict__ Wg, float* __restrict__ out, int batch) {
  __shared__ __align__(16) float Wl[N_ACTIONS * W_STRIDE];

  const int tid = threadIdx.x;
  // stage 8 KB of W into padded LDS layout (coalesced global read)
  for (int idx = tid; idx < N_ACTIONS * 256; idx += 256) {
    Wl[(idx >> 8) * W_STRIDE + (idx & 255)] = Wg[idx];
  }
  __syncthreads();

  for (int b = blockIdx.x * 256 + tid; b < batch; b += NBLK2 * 256) {
    const int act = a[b];
    const v4f* xp = reinterpret_cast<const v4f*>(x + (size_t)b * 16);
    const v4f x0 = __builtin_nontemporal_load(xp + 0);
    const v4f x1 = __builtin_nontemporal_load(xp + 1);
    const v4f x2 = __builtin_nontemporal_load(xp + 2);
    const v4f x3 = __builtin_nontemporal_load(xp + 3);

    const float* Wp = Wl + act * W_STRIDE;
    v4f* op = reinterpret_cast<v4f*>(out + (size_t)b * 16);
#pragma unroll
    for (int q = 0; q < 4; ++q) {
      v4f r;
#pragma unroll
      for (int t = 0; t < 4; ++t) {
        const int i = q * 4 + t;
        const v4f* wr = reinterpret_cast<const v4f*>(Wp + i * 16);
        const v4f w0 = wr[0];
        const v4f w1 = wr[1];
        const v4f w2 = wr[2];
        const v4f w3 = wr[3];
        r[t] = w0.x * x0.x + w0.y * x0.y + w0.z * x0.z + w0.w * x0.w +
               w1.x * x1.x + w1.y * x1.y + w1.z * x1.z + w1.w * x1.w +
               w2.x * x2.x + w2.y * x2.y + w2.z * x2.z + w2.w * x2.w +
               w3.x * x3.x + w3.y * x3.y + w3.z * x3.z + w3.w * x3.w;
      }
      __builtin_nontemporal_store(r, op + q);
    }
  }
}

extern "C" void kernel_launch(void* const* d_in, const int* in_sizes, int n_in,
                              void* d_out, int out_size, void* d_ws, size_t ws_size,
                              hipStream_t stream) {
  const float* x = (const float*)d_in[0];
  const int* a = (const int*)d_in[1];
  const float* A = (const float*)d_in[2];
  const float* Brep = (const float*)d_in[3];
  float* out = (float*)d_out;
  float* Wg = (float*)d_ws;  // 8*256 floats = 8 KB scratch

  const int batch = in_sizes[1];  // 500000

  compute_W_kernel<<<N_ACTIONS, 256, 0, stream>>>(A, Brep, Wg);
  gather_matvec_kernel<<<NBLK2, 256, 0, stream>>>(x, a, Wg, out, batch);
}

// Round 6
// 99.223 us; speedup vs baseline: 1.2608x; 1.2608x over previous
//
#include <hip/hip_runtime.h>
#include <hip/hip_bf16.h>

// Problem: out[b] = (inv(A[a[b]]) @ B_rep[a[b]] @ A[a[b]]) @ x[b]
// BATCH=500000, DIM=16, N_ACTIONS=8
// Inputs: x[500000*16] f32, a[500000] i32, A[8*16*16] f32, B_rep[8*16*16] f32
// Output: [500000*16] f32

#define N_ACTIONS 8
#define DIM 16
// LDS action stride: 260 % 32 == 4 dwords, so the 8 actions' uniform-offset
// 16B broadcast reads land in 8 disjoint 4-bank groups -> conflict-free.
// 260*4 = 1040 B keeps 16-B alignment for b128 reads.
#define W_STRIDE 260

typedef float v4f __attribute__((ext_vector_type(4)));

// ---------------------------------------------------------------------------
// Kernel 1: W[n] = inv(A[n]) @ B_rep[n] @ A[n], one block per action.
// Gauss-Jordan WITHOUT pivoting (A = I + 0.1*N(0,1), well-conditioned;
// validated absmax 0.0625 vs threshold 0.83). 2 barriers per iteration.
// ---------------------------------------------------------------------------
__global__ __launch_bounds__(256) void compute_W_kernel(
    const float* __restrict__ A, const float* __restrict__ Brep,
    float* __restrict__ Wg) {
  __shared__ float M[DIM][DIM + 1];
  __shared__ float Inv[DIM][DIM + 1];
  __shared__ float As[DIM][DIM + 1];
  __shared__ float Bs[DIM][DIM + 1];
  __shared__ float Cs[DIM][DIM + 1];

  const int n = blockIdx.x;
  const int tid = threadIdx.x;
  const int i = tid >> 4;
  const int j = tid & 15;

  const float a_ij = A[n * 256 + i * 16 + j];
  M[i][j] = a_ij;
  As[i][j] = a_ij;
  Bs[i][j] = Brep[n * 256 + i * 16 + j];
  Inv[i][j] = (i == j) ? 1.0f : 0.0f;
  __syncthreads();

#pragma unroll 1
  for (int k = 0; k < DIM; ++k) {
    // read phase: everything this thread needs, before anyone writes
    const float mkk = M[k][k];
    const float f = M[i][k];
    const float mkj = M[k][j];
    const float ikj = Inv[k][j];
    __syncthreads();
    const float pivinv = 1.0f / mkk;
    if (i == k) {
      M[k][j] = mkj * pivinv;
      Inv[k][j] = ikj * pivinv;
    } else {
      const float t = f * pivinv;
      M[i][j] -= t * mkj;
      Inv[i][j] -= t * ikj;
    }
    __syncthreads();
  }

  // C = B_rep @ A
  float acc = 0.0f;
#pragma unroll
  for (int k = 0; k < DIM; ++k) acc += Bs[i][k] * As[k][j];
  Cs[i][j] = acc;
  __syncthreads();

  // W = inv(A) @ C
  float w = 0.0f;
#pragma unroll
  for (int k = 0; k < DIM; ++k) w += Inv[i][k] * Cs[k][j];
  Wg[n * 256 + i * 16 + j] = w;
}

// ---------------------------------------------------------------------------
// Kernel 2: out[b] = W[a[b]] @ x[b]. One thread per sample (best measured
// config, round 4). W staged per block in padded LDS (broadcast reads,
// conflict-free). x loads / out stores 16B vectorized, CACHED (no
// nontemporal: 64B lane-stride pattern relies on L1/L2 line reuse across
// the 4 accesses -- NT bypass inflated DRAM traffic 2.3x in round 5).
// ---------------------------------------------------------------------------
__global__ __launch_bounds__(256) void gather_matvec_kernel(
    const float* __restrict__ x, const int* __restrict__ a,
    const float* __restrict__ Wg, float* __restrict__ out, int batch) {
  __shared__ __align__(16) float Wl[N_ACTIONS * W_STRIDE];

  const int tid = threadIdx.x;
  // stage 8 KB of W into padded LDS layout (coalesced global read)
  for (int idx = tid; idx < N_ACTIONS * 256; idx += 256) {
    Wl[(idx >> 8) * W_STRIDE + (idx & 255)] = Wg[idx];
  }
  __syncthreads();

  const int b = blockIdx.x * 256 + tid;
  if (b >= batch) return;

  const int act = a[b];
  const v4f* xp = reinterpret_cast<const v4f*>(x + (size_t)b * 16);
  const v4f x0 = xp[0];
  const v4f x1 = xp[1];
  const v4f x2 = xp[2];
  const v4f x3 = xp[3];

  const float* Wp = Wl + act * W_STRIDE;
  v4f* op = reinterpret_cast<v4f*>(out + (size_t)b * 16);
#pragma unroll
  for (int q = 0; q < 4; ++q) {
    v4f r;
#pragma unroll
    for (int t = 0; t < 4; ++t) {
      const int i = q * 4 + t;
      const v4f* wr = reinterpret_cast<const v4f*>(Wp + i * 16);
      const v4f w0 = wr[0];
      const v4f w1 = wr[1];
      const v4f w2 = wr[2];
      const v4f w3 = wr[3];
      r[t] = w0.x * x0.x + w0.y * x0.y + w0.z * x0.z + w0.w * x0.w +
             w1.x * x1.x + w1.y * x1.y + w1.z * x1.z + w1.w * x1.w +
             w2.x * x2.x + w2.y * x2.y + w2.z * x2.z + w2.w * x2.w +
             w3.x * x3.x + w3.y * x3.y + w3.z * x3.z + w3.w * x3.w;
    }
    op[q] = r;
  }
}

extern "C" void kernel_launch(void* const* d_in, const int* in_sizes, int n_in,
                              void* d_out, int out_size, void* d_ws, size_t ws_size,
                              hipStream_t stream) {
  const float* x = (const float*)d_in[0];
  const int* a = (const int*)d_in[1];
  const float* A = (const float*)d_in[2];
  const float* Brep = (const float*)d_in[3];
  float* out = (float*)d_out;
  float* Wg = (float*)d_ws;  // 8*256 floats = 8 KB scratch

  const int batch = in_sizes[1];  // 500000

  compute_W_kernel<<<N_ACTIONS, 256, 0, stream>>>(A, Brep, Wg);
  const int blocks = (batch + 255) / 256;
  gather_matvec_kernel<<<blocks, 256, 0, stream>>>(x, a, Wg, out, batch);
}